// Round 17
// baseline (973.682 us; speedup 1.0000x reference)
//
#include <hip/hip_runtime.h>
#include <cstdint>
#include <cstddef>

#define NN 50000
#define EE 800000
#define GG 8

typedef unsigned int u32;
typedef unsigned short u16;
typedef __attribute__((ext_vector_type(8))) short short8v;   // 8 bf16 = 4 VGPRs (A/B frag)
typedef __attribute__((ext_vector_type(4))) float f32x4;     // C/D frag

__device__ __forceinline__ u16 f2bf(float f){
  u32 b = __float_as_uint(f);
  u32 r = b + 0x7fffu + ((b>>16)&1u);
  return (u16)(r>>16);
}
__device__ __forceinline__ float bf2f(u16 v){ return __uint_as_float(((u32)v)<<16); }
__device__ __forceinline__ u32 pk2(float a, float b){ return (u32)f2bf(a) | ((u32)f2bf(b)<<16); }
__device__ __forceinline__ u32 encf(float f){
  u32 b = __float_as_uint(f);
  return (b & 0x80000000u) ? ~b : (b | 0x80000000u);
}
__device__ __forceinline__ float decf(u32 u){
  u32 b = (u & 0x80000000u) ? (u ^ 0x80000000u) : ~u;
  return __uint_as_float(b);
}
// packed bf16 pair add (lo,hi in one u32)
__device__ __forceinline__ u32 addpk(u32 a, u32 b){
  float lo = __uint_as_float(a<<16) + __uint_as_float(b<<16);
  float hi = __uint_as_float(a & 0xffff0000u) + __uint_as_float(b & 0xffff0000u);
  return (u32)f2bf(lo) | ((u32)f2bf(hi)<<16);
}
// load 8 consecutive f32 -> bf16x8 fragment
__device__ __forceinline__ short8v ld8bf(const float* p){
  float4 f0 = *(const float4*)p;
  float4 f1 = *(const float4*)(p+4);
  uint4 u;
  u.x = pk2(f0.x,f0.y); u.y = pk2(f0.z,f0.w);
  u.z = pk2(f1.x,f1.y); u.w = pk2(f1.z,f1.w);
  return *(short8v*)&u;
}

// ---------------- CSR build ----------------
__global__ void k_count(const int* __restrict__ ei, int* __restrict__ cnt){
  int e = blockIdx.x*256 + threadIdx.x;
  if (e < EE) atomicAdd(&cnt[ei[EE + e]], 1);
}

__global__ __launch_bounds__(1024) void k_scan(const int* __restrict__ CNT, int* __restrict__ OFF, int* __restrict__ CUR){
  const int CH = (NN + 1023)/1024;   // 49
  __shared__ int sums[1024];
  int tid = threadIdx.x;
  int b = tid*CH, e = b+CH; if (e > NN) e = NN;
  int s = 0;
  for (int i=b;i<e;++i) s += CNT[i];
  sums[tid] = s;
  __syncthreads();
  for (int o=1;o<1024;o<<=1){
    int x = (tid>=o) ? sums[tid-o] : 0;
    __syncthreads();
    sums[tid] += x;
    __syncthreads();
  }
  int excl = sums[tid] - s;
  for (int i=b;i<e;++i){
    OFF[i]=excl; CUR[i]=excl; excl += CNT[i];
  }
  if (tid==1023) OFF[NN] = sums[1023];
}

__global__ void k_scatter(const int* __restrict__ ei, int* __restrict__ cur,
                          int* __restrict__ csr, int* __restrict__ srcs){
  int e = blockIdx.x*256 + threadIdx.x;
  if (e < EE){
    int s = ei[e], d = ei[EE+e];
    int p = atomicAdd(&cur[d], 1);
    csr[p] = e; srcs[p] = s;
  }
}

// ---------------- weight prep: bf16 transposed [n][k] layouts ----------------
// 0:ee1t 4096:ee2t 8192:we1t 16384:we2t 20480:ne1t 53248:ne2t 61440:g1lt 69632:g1rt
// 77824:g2lt 86016:g2rt   total 94208
__global__ __launch_bounds__(256) void k_prep(const float* __restrict__ W_ee1,
    const float* __restrict__ W_ee2, const float* __restrict__ W_g1we,
    const float* __restrict__ W_g2we, const float* __restrict__ W_ne1,
    const float* __restrict__ W_ne2, const float* __restrict__ W_g1l,
    const float* __restrict__ W_g1r, const float* __restrict__ W_g2l,
    const float* __restrict__ W_g2r, u16* __restrict__ TW){
  int i = blockIdx.x*256 + threadIdx.x;
  if (i < 4096){
    int n=i>>6, k=i&63; TW[i] = f2bf(W_ee1[k*64+n]);
  } else if (i < 8192){
    int j=i-4096; int n=j>>6, k=j&63; TW[i] = f2bf(W_ee2[k*64+n]);
  } else if (i < 16384){
    int j=i-8192; int n=j>>6, k=j&63; TW[i] = f2bf(W_g1we[k*128+n]);
  } else if (i < 20480){
    int j=i-16384; int n=j>>6, k=j&63; TW[i] = f2bf(W_g2we[k*64+n]);
  } else if (i < 53248){
    int j=i-20480; int n=j>>8, k=j&255; TW[i] = f2bf(W_ne1[k*128+n]);
  } else if (i < 61440){
    int j=i-53248; int n=j>>7, k=j&127; TW[i] = f2bf(W_ne2[k*64+n]);
  } else if (i < 69632){
    int j=i-61440; int n=j>>6, k=j&63; TW[i] = f2bf(W_g1l[k*128+n]);
  } else if (i < 77824){
    int j=i-69632; int n=j>>6, k=j&63; TW[i] = f2bf(W_g1r[k*128+n]);
  } else if (i < 86016){
    int j=i-77824; int n=j>>7, k=j&127; TW[i] = f2bf(W_g2l[k*64+n]);
  } else if (i < 94208){
    int j=i-86016; int n=j>>7, k=j&127; TW[i] = f2bf(W_g2r[k*64+n]);
  }
}

// ---------------- MFMA linear: Y = act(X @ W + b), 64 rows/block ----------------
template<int CI, int CO, int ACT, int BFO, int BFI>
__global__ __launch_bounds__(256) void k_linm(const void* __restrict__ Xv, const u16* __restrict__ WT,
    const float* __restrict__ Bb, void* __restrict__ Yv, int R){
  __shared__ u16 xs[64*(CI+8)];
  int tid = threadIdx.x;
  int r0 = blockIdx.x*64;
  if (BFI){
    const u16* X = (const u16*)Xv;
    for (int i=tid; i<64*CI/8; i+=256){
      int row = i/(CI/8), c = i%(CI/8);
      uint4 v = make_uint4(0,0,0,0);
      if (r0+row < R) v = ((const uint4*)(X + (size_t)(r0+row)*CI))[c];
      *(uint4*)&xs[row*(CI+8) + c*8] = v;
    }
  } else {
    const float* X = (const float*)Xv;
    for (int i=tid; i<64*CI/4; i+=256){
      int row = i/(CI/4), c = i%(CI/4);
      float4 v = make_float4(0,0,0,0);
      if (r0+row < R) v = ((const float4*)(X + (size_t)(r0+row)*CI))[c];
      *(uint2*)&xs[row*(CI+8) + c*4] = make_uint2(pk2(v.x,v.y), pk2(v.z,v.w));
    }
  }
  __syncthreads();
  int l = tid & 63, w = tid >> 6;
  int am = l & 15, kg = l >> 4;
  const int NT = CO/16;
  f32x4 acc[NT];
#pragma unroll
  for (int nt=0;nt<NT;++nt) acc[nt] = (f32x4){0.f,0.f,0.f,0.f};
#pragma unroll
  for (int kc=0; kc<CI/32; ++kc){
    short8v a = *(const short8v*)&xs[(w*16+am)*(CI+8) + kc*32 + kg*8];
#pragma unroll
    for (int nt=0;nt<NT;++nt){
      short8v b = *(const short8v*)&WT[(size_t)(nt*16+am)*CI + kc*32 + kg*8];
      acc[nt] = __builtin_amdgcn_mfma_f32_16x16x32_bf16(a, b, acc[nt], 0, 0, 0);
    }
  }
#pragma unroll
  for (int nt=0;nt<NT;++nt){
    int col = nt*16 + am;
    float bb = Bb[col];
#pragma unroll
    for (int j=0;j<4;++j){
      int row = r0 + w*16 + kg*4 + j;
      if (row < R){
        float v = acc[nt][j] + bb;
        if (ACT==1) v = fmaxf(v, 0.f);
        if (BFO) ((u16*)Yv)[(size_t)row*CO + col] = f2bf(v);
        else     ((float*)Yv)[(size_t)row*CO + col] = v;
      }
    }
  }
}

// ---------------- dual MFMA linear: Y1 = X@W1+b1, Y2 = X@W2+b2 (bf16 out) ----------------
template<int CI, int CO>
__global__ __launch_bounds__(256) void k_linm2(const float* __restrict__ X,
    const u16* __restrict__ WT1, const float* __restrict__ B1,
    const u16* __restrict__ WT2, const float* __restrict__ B2,
    u16* __restrict__ Y1, u16* __restrict__ Y2, int R){
  __shared__ u16 xs[64*(CI+8)];
  int tid = threadIdx.x;
  int r0 = blockIdx.x*64;
  for (int i=tid; i<64*CI/4; i+=256){
    int row = i/(CI/4), c = i%(CI/4);
    float4 v = make_float4(0,0,0,0);
    if (r0+row < R) v = ((const float4*)(X + (size_t)(r0+row)*CI))[c];
    *(uint2*)&xs[row*(CI+8) + c*4] = make_uint2(pk2(v.x,v.y), pk2(v.z,v.w));
  }
  __syncthreads();
  int l = tid & 63, w = tid >> 6;
  int am = l & 15, kg = l >> 4;
  const int NT = CO/16;
  f32x4 acc1[NT], acc2[NT];
#pragma unroll
  for (int nt=0;nt<NT;++nt){ acc1[nt] = (f32x4){0.f,0.f,0.f,0.f}; acc2[nt] = (f32x4){0.f,0.f,0.f,0.f}; }
#pragma unroll
  for (int kc=0; kc<CI/32; ++kc){
    short8v a = *(const short8v*)&xs[(w*16+am)*(CI+8) + kc*32 + kg*8];
#pragma unroll
    for (int nt=0;nt<NT;++nt){
      short8v b1 = *(const short8v*)&WT1[(size_t)(nt*16+am)*CI + kc*32 + kg*8];
      acc1[nt] = __builtin_amdgcn_mfma_f32_16x16x32_bf16(a, b1, acc1[nt], 0, 0, 0);
      short8v b2 = *(const short8v*)&WT2[(size_t)(nt*16+am)*CI + kc*32 + kg*8];
      acc2[nt] = __builtin_amdgcn_mfma_f32_16x16x32_bf16(a, b2, acc2[nt], 0, 0, 0);
    }
  }
#pragma unroll
  for (int nt=0;nt<NT;++nt){
    int col = nt*16 + am;
    float bb1 = B1[col], bb2 = B2[col];
#pragma unroll
    for (int j=0;j<4;++j){
      int row = r0 + w*16 + kg*4 + j;
      if (row < R){
        Y1[(size_t)row*CO + col] = f2bf(acc1[nt][j] + bb1);
        Y2[(size_t)row*CO + col] = f2bf(acc2[nt][j] + bb2);
      }
    }
  }
}

// ---------------- mega1: alpha1 + edge encoder, EDGE-ID order, 64 edges/block ----------------
// A-fragments loaded direct from global f32 (no ea LDS); MFMA overlaps xsum staging.
__global__ __launch_bounds__(256) void k_mega1(const float* __restrict__ EA,
    const int* __restrict__ EI,
    const u16* __restrict__ TW, const float* __restrict__ B1, const float* __restrict__ B2,
    const u16* __restrict__ XLb, const u16* __restrict__ XRb, const float* __restrict__ ATT,
    float* __restrict__ OUT_ER, float* __restrict__ ALPHA){
  __shared__ u16 buf_s[64*72];       // mid only
  __shared__ u16 xsum[64*136];       // bf16(xl+xr); later reused as er f32 [64][68]
  __shared__ float al_s[256];
  __shared__ int ssrc[64], sdst[64];
  float* er_s = (float*)xsum;        // alias
  int tid = threadIdx.x;
  int e0 = blockIdx.x*64;
  if (tid < 64){ ssrc[tid]=EI[e0+tid]; sdst[tid]=EI[EE+e0+tid]; }
  __syncthreads();                    // B1
  // xsum staging (stores; visible after B2)
#pragma unroll
  for (int i=0;i<4;++i){
    int item = tid + i*256;
    int row = item>>4, c = item&15;
    uint4 xa = ((const uint4*)(XLb + (size_t)ssrc[row]*128))[c];
    uint4 xb = ((const uint4*)(XRb + (size_t)sdst[row]*128))[c];
    uint4 r;
    r.x = addpk(xa.x, xb.x); r.y = addpk(xa.y, xb.y);
    r.z = addpk(xa.z, xb.z); r.w = addpk(xa.w, xb.w);
    *(uint4*)&xsum[row*136 + c*8] = r;
  }
  int l = tid & 63, w = tid >> 6;
  int am = l & 15, kg = l >> 4;
  // A-fragments direct from global (overlaps staging above)
  const float* arow = EA + (size_t)(e0 + w*16 + am)*64;
  short8v a0 = ld8bf(arow + kg*8);
  short8v a1 = ld8bf(arow + 32 + kg*8);
  // alpha1 we1 GEMM (64->128)
  f32x4 accw[8];
#pragma unroll
  for (int nt=0;nt<8;++nt) accw[nt] = (f32x4){0.f,0.f,0.f,0.f};
#pragma unroll
  for (int nt=0;nt<8;++nt){
    short8v b0 = *(const short8v*)&TW[8192 + (nt*16+am)*64 + 0  + kg*8];
    short8v b1 = *(const short8v*)&TW[8192 + (nt*16+am)*64 + 32 + kg*8];
    accw[nt] = __builtin_amdgcn_mfma_f32_16x16x32_bf16(a0, b0, accw[nt], 0, 0, 0);
    accw[nt] = __builtin_amdgcn_mfma_f32_16x16x32_bf16(a1, b1, accw[nt], 0, 0, 0);
  }
  // edge encoder layer 1 -> mid (buf_s)
  {
    f32x4 acc[4];
#pragma unroll
    for (int nt=0;nt<4;++nt) acc[nt] = (f32x4){0.f,0.f,0.f,0.f};
#pragma unroll
    for (int nt=0;nt<4;++nt){
      short8v b0 = *(const short8v*)&TW[(nt*16+am)*64 + 0  + kg*8];
      short8v b1 = *(const short8v*)&TW[(nt*16+am)*64 + 32 + kg*8];
      acc[nt] = __builtin_amdgcn_mfma_f32_16x16x32_bf16(a0, b0, acc[nt], 0, 0, 0);
      acc[nt] = __builtin_amdgcn_mfma_f32_16x16x32_bf16(a1, b1, acc[nt], 0, 0, 0);
    }
#pragma unroll
    for (int nt=0;nt<4;++nt){
      int col = nt*16 + am;
      float bb = B1[col];
#pragma unroll
      for (int j=0;j<4;++j){
        float v = fmaxf(acc[nt][j] + bb, 0.f);
        buf_s[(w*16 + kg*4 + j)*72 + col] = f2bf(v);
      }
    }
  }
  __syncthreads();                    // B2: xsum + mid visible
  // alpha1 epilogue (reads xsum)
  {
    float attv[8];
#pragma unroll
    for (int nt=0;nt<8;++nt) attv[nt] = ATT[nt*16 + am];
#pragma unroll
    for (int j=0;j<4;++j){
      int eloc = w*16 + kg*4 + j;
      const u16* xsp = &xsum[eloc*136 + am];
#pragma unroll
      for (int h=0;h<4;++h){
        float sum = 0.f;
#pragma unroll
        for (int q=0;q<2;++q){
          int nt = h*2 + q;
          float s = accw[nt][j] + bf2f(xsp[nt*16]);
          s = s>0.f ? s : 0.2f*s;
          sum += s * attv[nt];
        }
        sum += __shfl_xor(sum,1); sum += __shfl_xor(sum,2);
        sum += __shfl_xor(sum,4); sum += __shfl_xor(sum,8);
        if (am==0) al_s[eloc*4 + h] = sum;
      }
    }
  }
  // edge encoder layer 2 (reads buf_s mid) -> regs
  f32x4 acc2[4];
  {
    short8v m0 = *(const short8v*)&buf_s[(w*16+am)*72 + 0  + kg*8];
    short8v m1 = *(const short8v*)&buf_s[(w*16+am)*72 + 32 + kg*8];
#pragma unroll
    for (int nt=0;nt<4;++nt) acc2[nt] = (f32x4){0.f,0.f,0.f,0.f};
#pragma unroll
    for (int nt=0;nt<4;++nt){
      short8v b0 = *(const short8v*)&TW[4096 + (nt*16+am)*64 + 0  + kg*8];
      short8v b1 = *(const short8v*)&TW[4096 + (nt*16+am)*64 + 32 + kg*8];
      acc2[nt] = __builtin_amdgcn_mfma_f32_16x16x32_bf16(m0, b0, acc2[nt], 0, 0, 0);
      acc2[nt] = __builtin_amdgcn_mfma_f32_16x16x32_bf16(m1, b1, acc2[nt], 0, 0, 0);
    }
  }
  __syncthreads();                    // B3: xsum reads done -> er_s write safe
#pragma unroll
  for (int nt=0;nt<4;++nt){
    int col = nt*16 + am;
    float bb = B2[col];
#pragma unroll
    for (int j=0;j<4;++j) er_s[(w*16 + kg*4 + j)*68 + col] = acc2[nt][j] + bb;
  }
  __syncthreads();                    // B4: er_s + al_s ready
  ALPHA[(size_t)e0*4 + tid] = al_s[tid];
  {
    int col4 = tid & 15;
#pragma unroll
    for (int p=0;p<4;++p){
      int row = p*16 + (tid>>4);
      float4 v = *(const float4*)&er_s[row*68 + col4*4];
      *(float4*)(OUT_ER + (size_t)(e0+row)*64 + col4*4) = v;
    }
  }
}

// ---------------- alpha2: EDGE-ID order, direct A-frags, xsum epilogue (H=2, HD=64) --------
__global__ __launch_bounds__(256) void k_alpha2m(const float* __restrict__ EA,
    const int* __restrict__ EI,
    const u16* __restrict__ TW, const u16* __restrict__ XLb, const u16* __restrict__ XRb,
    const float* __restrict__ ATT, float* __restrict__ ALPHA){
  __shared__ u16 xsum[64*72];
  __shared__ float al_s[128];
  __shared__ int ssrc[64], sdst[64];
  int tid = threadIdx.x;
  int e0 = blockIdx.x*64;
  if (tid < 64){ ssrc[tid]=EI[e0+tid]; sdst[tid]=EI[EE+e0+tid]; }
  __syncthreads();
#pragma unroll
  for (int i=0;i<2;++i){
    int item = tid + i*256;
    int row = item>>3, c = item&7;
    uint4 xa = ((const uint4*)(XLb + (size_t)ssrc[row]*64))[c];
    uint4 xb = ((const uint4*)(XRb + (size_t)sdst[row]*64))[c];
    uint4 r;
    r.x = addpk(xa.x, xb.x); r.y = addpk(xa.y, xb.y);
    r.z = addpk(xa.z, xb.z); r.w = addpk(xa.w, xb.w);
    *(uint4*)&xsum[row*72 + c*8] = r;
  }
  int l = tid & 63, w = tid >> 6;
  int am = l & 15, kg = l >> 4;
  const float* arow = EA + (size_t)(e0 + w*16 + am)*64;
  short8v a0 = ld8bf(arow + kg*8);
  short8v a1 = ld8bf(arow + 32 + kg*8);
  f32x4 acc[4];
#pragma unroll
  for (int nt=0;nt<4;++nt) acc[nt] = (f32x4){0.f,0.f,0.f,0.f};
#pragma unroll
  for (int nt=0;nt<4;++nt){
    short8v b0 = *(const short8v*)&TW[16384 + (nt*16+am)*64 + 0  + kg*8];
    short8v b1 = *(const short8v*)&TW[16384 + (nt*16+am)*64 + 32 + kg*8];
    acc[nt] = __builtin_amdgcn_mfma_f32_16x16x32_bf16(a0, b0, acc[nt], 0, 0, 0);
    acc[nt] = __builtin_amdgcn_mfma_f32_16x16x32_bf16(a1, b1, acc[nt], 0, 0, 0);
  }
  __syncthreads();   // xsum ready
  float attv[4];
#pragma unroll
  for (int nt=0;nt<4;++nt) attv[nt] = ATT[nt*16 + am];
#pragma unroll
  for (int j=0;j<4;++j){
    int eloc = w*16 + kg*4 + j;
    const u16* xsp = &xsum[eloc*72 + am];
#pragma unroll
    for (int h=0;h<2;++h){
      float sum = 0.f;
#pragma unroll
      for (int q=0;q<2;++q){
        int nt = h*2 + q;
        float s = acc[nt][j] + bf2f(xsp[nt*16]);
        s = s>0.f ? s : 0.2f*s;
        sum += s * attv[nt];
      }
      sum += __shfl_xor(sum,1); sum += __shfl_xor(sum,2);
      sum += __shfl_xor(sum,4); sum += __shfl_xor(sum,8);
      if (am==0) al_s[eloc*2 + h] = sum;
    }
  }
  __syncthreads();
  if (tid < 128) ALPHA[(size_t)e0*2 + tid] = al_s[tid];
}

// ---------------- gather layer 1: online softmax + LN + ELU fused ----------------
__global__ __launch_bounds__(256) void k_gather1(const u16* __restrict__ XLb, const float* __restrict__ ALPHA,
    const float* __restrict__ BIAS, const float* __restrict__ G_, const float* __restrict__ B_,
    const int* __restrict__ CSR, const int* __restrict__ SRCS, const int* __restrict__ OFF,
    float* __restrict__ OUT){
  int t = threadIdx.x & 63;
  int n = blockIdx.x*4 + (threadIdx.x >> 6);
  int h = t >> 4;
  int beg = OFF[n], end = OFF[n+1];
  float m = -INFINITY, l = 0.f, a0 = 0.f, a1 = 0.f;
  for (int i=beg; i<end; ++i){
    int e = CSR[i];
    int s = SRCS[i];
    float al = ALPHA[(size_t)e*4 + h];
    u32 v = *(const u32*)(XLb + (size_t)s*128 + 2*t);
    float x0 = __uint_as_float(v<<16);
    float x1 = __uint_as_float(v & 0xffff0000u);
    if (al > m){
      float sc = __expf(m - al);   // m==-inf -> 0
      a0 = a0*sc + x0; a1 = a1*sc + x1; l = l*sc + 1.f; m = al;
    } else {
      float p = __expf(al - m);
      a0 += p*x0; a1 += p*x1; l += p;
    }
  }
  float inv = 1.f/(l + 1e-16f);
  float o0 = a0*inv + BIAS[2*t];
  float o1 = a1*inv + BIAS[2*t+1];
  float s = o0 + o1, q = o0*o0 + o1*o1;
#pragma unroll
  for (int o=1;o<64;o<<=1){ s += __shfl_xor(s,o); q += __shfl_xor(q,o); }
  float mean = s * (1.f/128.f);
  float var  = q * (1.f/128.f) - mean*mean;
  float r = rsqrtf(var + 1e-5f);
  float y0 = (o0-mean)*r*G_[2*t]   + B_[2*t];
  float y1 = (o1-mean)*r*G_[2*t+1] + B_[2*t+1];
  y0 = y0>0.f ? y0 : __expf(y0)-1.f;
  y1 = y1>0.f ? y1 : __expf(y1)-1.f;
  *(float2*)(OUT + (size_t)n*128 + 2*t) = make_float2(y0,y1);
}

// ---------------- gather layer 2: online softmax, raw out (no LDS, high occupancy) ----------------
__global__ __launch_bounds__(256) void k_gather2(const u16* __restrict__ XLb, const float* __restrict__ ALPHA,
    const float* __restrict__ BIAS, const int* __restrict__ CSR, const int* __restrict__ SRCS,
    const int* __restrict__ OFF, float* __restrict__ OUT){
  int t = threadIdx.x & 63;
  int n = blockIdx.x*4 + (threadIdx.x >> 6);
  int h = t >> 5;
  int beg = OFF[n], end = OFF[n+1];
  float m = -INFINITY, l = 0.f, a0 = 0.f;
  for (int i=beg; i<end; ++i){
    int e = CSR[i];
    int s = SRCS[i];
    float al = ALPHA[(size_t)e*2 + h];
    float xlv = bf2f(XLb[(size_t)s*64 + t]);
    if (al > m){
      float sc = __expf(m - al);
      a0 = a0*sc + xlv; l = l*sc + 1.f; m = al;
    } else {
      float p = __expf(al - m);
      a0 += p*xlv; l += p;
    }
  }
  float inv = 1.f/(l + 1e-16f);
  OUT[(size_t)n*64 + t] = a0*inv + BIAS[t];
}

// ---------------- LN(64) + residual GEMV + ELU + gate MLP fused (LDS GEMV) ----------------
__global__ __launch_bounds__(256) void k_res_gate(const float* __restrict__ GO, const float* __restrict__ H0,
    const float* __restrict__ RPW, const float* __restrict__ RPB_, const float* __restrict__ G_,
    const float* __restrict__ B_, const float* __restrict__ GT1, const float* __restrict__ GTB1,
    const float* __restrict__ GT2, const float* __restrict__ GTB2,
    float* __restrict__ NE, float* __restrict__ GATE){
  __shared__ float rlt[64*68];
  __shared__ float glt[64*68];
  __shared__ float xsw[4][64];
  __shared__ float ysw[4][64];
  int tid = threadIdx.x, t = tid & 63, wv = tid >> 6;
  for (int i=tid; i<64*64; i+=256){
    int k = i>>6, c = i&63;
    rlt[c*68+k] = RPW[i];
    glt[c*68+k] = GT1[i];
  }
  __syncthreads();
  int n = blockIdx.x*4 + wv;
  float x = GO[(size_t)n*64 + t];
  float s = x, q = x*x;
#pragma unroll
  for (int o=1;o<64;o<<=1){ s += __shfl_xor(s,o); q += __shfl_xor(q,o); }
  float mean = s * (1.f/64.f);
  float var  = q * (1.f/64.f) - mean*mean;
  float r = rsqrtf(var + 1e-5f);
  float ln = (x-mean)*r*G_[t] + B_[t];
  xsw[wv][t] = H0[(size_t)n*64 + t];   // same-wave write->read, lockstep safe
  float acc = 0.f;
#pragma unroll
  for (int k4=0;k4<16;++k4){
    float4 w  = *(const float4*)&rlt[t*68 + k4*4];
    float4 xv = *(const float4*)&xsw[wv][k4*4];
    acc += xv.x*w.x + xv.y*w.y + xv.z*w.z + xv.w*w.w;
  }
  float y = ln + acc + RPB_[t];
  y = y>0.f ? y : __expf(y)-1.f;
  NE[(size_t)n*64+t] = y;
  ysw[wv][t] = y;
  float mid = 0.f;
#pragma unroll
  for (int k4=0;k4<16;++k4){
    float4 w  = *(const float4*)&glt[t*68 + k4*4];
    float4 xv = *(const float4*)&ysw[wv][k4*4];
    mid += xv.x*w.x + xv.y*w.y + xv.z*w.z + xv.w*w.w;
  }
  float p = fmaxf(mid + GTB1[t], 0.f) * GT2[t];
#pragma unroll
  for (int o=1;o<64;o<<=1) p += __shfl_xor(p,o);
  if (t==0) GATE[n] = p + GTB2[0];
}

// ---------------- pooling ----------------
__global__ __launch_bounds__(256) void k_pool_max(const float* __restrict__ GATE, const int* __restrict__ BATCH, u32* __restrict__ GMAX){
  __shared__ u32 lmax[GG];
  int tid = threadIdx.x;
  if (tid < GG) lmax[tid] = 0u;
  __syncthreads();
  int base = blockIdx.x*1024;
#pragma unroll
  for (int j=0;j<4;++j){
    int i = base + j*256 + tid;
    if (i < NN) atomicMax(&lmax[BATCH[i]], encf(GATE[i]));
  }
  __syncthreads();
  if (tid < GG && lmax[tid] != 0u) atomicMax(&GMAX[tid], lmax[tid]);
}

__global__ __launch_bounds__(64) void k_pool_acc(const float* __restrict__ NE, const float* __restrict__ GATE,
    const int* __restrict__ BATCH, const u32* __restrict__ GMAX, float* __restrict__ GACC, float* __restrict__ GDEN){
  int t = threadIdx.x;
  int n0 = blockIdx.x*256;
  int n1 = n0+256; if (n1 > NN) n1 = NN;
  int curg = -1; float acc = 0.f, dl = 0.f, gm = 0.f;
  for (int n=n0; n<n1; ++n){
    int g = BATCH[n];
    if (g != curg){
      if (curg >= 0){ atomicAdd(&GACC[curg*64+t], acc); if (t==0) atomicAdd(&GDEN[curg], dl); }
      curg = g; acc = 0.f; dl = 0.f;
      float d = decf(GMAX[g]);
      gm = isfinite(d) ? d : 0.f;
    }
    float p = __expf(GATE[n] - gm);
    acc += p * NE[(size_t)n*64 + t];
    if (t==0) dl += p;
  }
  if (curg >= 0){ atomicAdd(&GACC[curg*64+t], acc); if (t==0) atomicAdd(&GDEN[curg], dl); }
}

__global__ __launch_bounds__(64) void k_scene(const float* __restrict__ GACC, const float* __restrict__ GDEN,
    const float* __restrict__ W1, const float* __restrict__ B1, const float* __restrict__ W2,
    const float* __restrict__ B2, float* __restrict__ Z){
  __shared__ float gv[GG][64];
  __shared__ float md[GG][64];
  int t = threadIdx.x;
  for (int g=0; g<GG; ++g) gv[g][t] = GACC[g*64+t] / (GDEN[g] + 1e-16f);
  __syncthreads();
  for (int g=0; g<GG; ++g){
    float m = 0.f;
    for (int k=0;k<64;++k) m += gv[g][k]*W1[k*64+t];
    md[g][t] = fmaxf(m + B1[t], 0.f);
  }
  __syncthreads();
  if (t < 32){
    for (int g=0; g<GG; ++g){
      float o = 0.f;
      for (int k=0;k<64;++k) o += md[g][k]*W2[k*32+t];
      Z[g*32+t] = o + B2[t];
    }
  }
}

// ---------------- launch ----------------
extern "C" void kernel_launch(void* const* d_in, const int* in_sizes, int n_in,
                              void* d_out, int out_size, void* d_ws, size_t ws_size,
                              hipStream_t stream){
  const float* x   = (const float*)d_in[0];
  const int* ei    = (const int*)d_in[1];
  const float* ea  = (const float*)d_in[2];
  const int* batch = (const int*)d_in[3];
  const float* ne_w1 = (const float*)d_in[4];  const float* ne_b1 = (const float*)d_in[5];
  const float* ne_w2 = (const float*)d_in[6];  const float* ne_b2 = (const float*)d_in[7];
  const float* ee_w1 = (const float*)d_in[8];  const float* ee_b1 = (const float*)d_in[9];
  const float* ee_w2 = (const float*)d_in[10]; const float* ee_b2 = (const float*)d_in[11];
  const float* g1_wl = (const float*)d_in[12]; const float* g1_bl = (const float*)d_in[13];
  const float* g1_wr = (const float*)d_in[14]; const float* g1_br = (const float*)d_in[15];
  const float* g1_we = (const float*)d_in[16];
  const float* g1_att= (const float*)d_in[17]; const float* g1_b  = (const float*)d_in[18];
  const float* n1_g  = (const float*)d_in[19]; const float* n1_b  = (const float*)d_in[20];
  const float* g2_wl = (const float*)d_in[21]; const float* g2_bl = (const float*)d_in[22];
  const float* g2_wr = (const float*)d_in[23]; const float* g2_br = (const float*)d_in[24];
  const float* g2_we = (const float*)d_in[25];
  const float* g2_att= (const float*)d_in[26]; const float* g2_b  = (const float*)d_in[27];
  const float* n2_g  = (const float*)d_in[28]; const float* n2_b  = (const float*)d_in[29];
  const float* rp_w  = (const float*)d_in[30]; const float* rp_b  = (const float*)d_in[31];
  const float* gt_w1 = (const float*)d_in[32]; const float* gt_b1 = (const float*)d_in[33];
  const float* gt_w2 = (const float*)d_in[34]; const float* gt_b2 = (const float*)d_in[35];
  const float* se_w1 = (const float*)d_in[36]; const float* se_b1 = (const float*)d_in[37];
  const float* se_w2 = (const float*)d_in[38]; const float* se_b2 = (const float*)d_in[39];

  char* ws = (char*)d_ws;
  size_t o = 0;
  auto alloc = [&](size_t bytes){ size_t r = o; o += (bytes + 255) & ~(size_t)255; return r; };
  float* h0    = (float*)(ws + alloc((size_t)NN*64*4));
  float* ta    = (float*)(ws + alloc((size_t)NN*128*4));   // node-enc mid (bf16), then alpha buffer
  float* tc    = (float*)(ws + alloc((size_t)NN*128*4));   // h1, then gather2 out
  u16*   xl1b  = (u16*)  (ws + alloc((size_t)NN*128*2));
  u16*   xr1b  = (u16*)  (ws + alloc((size_t)NN*128*2));
  u16*   xl2b  = (u16*)  (ws + alloc((size_t)NN*64*2));
  u16*   xr2b  = (u16*)  (ws + alloc((size_t)NN*64*2));
  float* gate  = (float*)(ws + alloc((size_t)NN*4));
  int*   cnt   = (int*)  (ws + alloc((size_t)NN*4));
  int*   off   = (int*)  (ws + alloc((size_t)(NN+1)*4));
  int*   csr   = (int*)  (ws + alloc((size_t)EE*4));
  int*   srcs  = (int*)  (ws + alloc((size_t)EE*4));
  u16*   tw    = (u16*)  (ws + alloc((size_t)94208*2));
  char*  poolb = ws + alloc(4096);
  u32*   gmax  = (u32*)poolb;
  float* gden  = (float*)(poolb + 64);
  float* gacc  = (float*)(poolb + 128);
  float* alphab= ta;                                       // alias: ta free after node encoder
  u16*   midb  = (u16*)ta;                                 // node-enc mid bf16 (dead before alpha)
  if (o > ws_size) return;

  float* out_z  = (float*)d_out;
  float* out_ne = out_z + 256;
  float* out_er = out_ne + (size_t)NN*64;

  // CSR by dst + weight prep
  hipMemsetAsync(cnt, 0, (size_t)NN*4, stream);
  hipMemsetAsync(poolb, 0, 4096, stream);
  k_count<<<(EE+255)/256, 256, 0, stream>>>(ei, cnt);
  k_scan<<<1, 1024, 0, stream>>>(cnt, off, cnt);
  k_scatter<<<(EE+255)/256, 256, 0, stream>>>(ei, cnt, csr, srcs);
  k_prep<<<368, 256, 0, stream>>>(ee_w1, ee_w2, g1_we, g2_we, ne_w1, ne_w2,
                                  g1_wl, g1_wr, g2_wl, g2_wr, tw);

  // node encoder (MFMA): x -> midb(bf16) -> h0(f32)
  k_linm<256,128,1,1,0><<<(NN+63)/64, 256, 0, stream>>>(x,    tw+20480, ne_b1, midb, NN);
  k_linm<128,64, 0,0,1><<<(NN+63)/64, 256, 0, stream>>>(midb, tw+53248, ne_b2, h0,   NN);

  // GAT layer 1 (+ fused edge encoder), edge-id order
  k_linm2<64,128><<<(NN+63)/64, 256, 0, stream>>>(h0, tw+61440, g1_bl, tw+69632, g1_br, xl1b, xr1b, NN);
  k_mega1<<<EE/64, 256, 0, stream>>>(ea, ei, tw, ee_b1, ee_b2,
                                     xl1b, xr1b, g1_att, out_er, alphab);
  k_gather1<<<NN/4, 256, 0, stream>>>(xl1b, alphab, g1_b, n1_g, n1_b, csr, srcs, off, tc);

  // GAT layer 2, edge-id order
  k_linm2<128,64><<<(NN+63)/64, 256, 0, stream>>>(tc, tw+77824, g2_bl, tw+86016, g2_br, xl2b, xr2b, NN);
  k_alpha2m<<<EE/64, 256, 0, stream>>>(ea, ei, tw, xl2b, xr2b, g2_att, alphab);
  k_gather2<<<NN/4, 256, 0, stream>>>(xl2b, alphab, g2_b, csr, srcs, off, tc);
  k_res_gate<<<NN/4, 256, 0, stream>>>(tc, h0, rp_w, rp_b, n2_g, n2_b,
                                       gt_w1, gt_b1, gt_w2, gt_b2, out_ne, gate);

  // pooling + scene encoder
  k_pool_max<<<(NN+1023)/1024, 256, 0, stream>>>(gate, batch, gmax);
  k_pool_acc<<<(NN+255)/256, 64, 0, stream>>>(out_ne, gate, batch, gmax, gacc, gden);
  k_scene<<<1, 64, 0, stream>>>(gacc, gden, se_w1, se_b1, se_w2, se_b2, out_z);
}

// Round 18
// 960.426 us; speedup vs baseline: 1.0138x; 1.0138x over previous
//
#include <hip/hip_runtime.h>
#include <cstdint>
#include <cstddef>

#define NN 50000
#define EE 800000
#define GG 8

typedef unsigned int u32;
typedef unsigned short u16;
typedef __attribute__((ext_vector_type(8))) short short8v;   // 8 bf16 = 4 VGPRs (A/B frag)
typedef __attribute__((ext_vector_type(4))) float f32x4;     // C/D frag

__device__ __forceinline__ u16 f2bf(float f){
  u32 b = __float_as_uint(f);
  u32 r = b + 0x7fffu + ((b>>16)&1u);
  return (u16)(r>>16);
}
__device__ __forceinline__ float bf2f(u16 v){ return __uint_as_float(((u32)v)<<16); }
__device__ __forceinline__ u32 pk2(float a, float b){ return (u32)f2bf(a) | ((u32)f2bf(b)<<16); }
__device__ __forceinline__ u32 encf(float f){
  u32 b = __float_as_uint(f);
  return (b & 0x80000000u) ? ~b : (b | 0x80000000u);
}
__device__ __forceinline__ float decf(u32 u){
  u32 b = (u & 0x80000000u) ? (u ^ 0x80000000u) : ~u;
  return __uint_as_float(b);
}
// packed bf16 pair add (lo,hi in one u32)
__device__ __forceinline__ u32 addpk(u32 a, u32 b){
  float lo = __uint_as_float(a<<16) + __uint_as_float(b<<16);
  float hi = __uint_as_float(a & 0xffff0000u) + __uint_as_float(b & 0xffff0000u);
  return (u32)f2bf(lo) | ((u32)f2bf(hi)<<16);
}

// ---------------- CSR build ----------------
__global__ void k_count(const int* __restrict__ ei, int* __restrict__ cnt){
  int e = blockIdx.x*256 + threadIdx.x;
  if (e < EE) atomicAdd(&cnt[ei[EE + e]], 1);
}

__global__ __launch_bounds__(1024) void k_scan(const int* __restrict__ CNT, int* __restrict__ OFF, int* __restrict__ CUR){
  const int CH = (NN + 1023)/1024;   // 49
  __shared__ int sums[1024];
  int tid = threadIdx.x;
  int b = tid*CH, e = b+CH; if (e > NN) e = NN;
  int s = 0;
  for (int i=b;i<e;++i) s += CNT[i];
  sums[tid] = s;
  __syncthreads();
  for (int o=1;o<1024;o<<=1){
    int x = (tid>=o) ? sums[tid-o] : 0;
    __syncthreads();
    sums[tid] += x;
    __syncthreads();
  }
  int excl = sums[tid] - s;
  for (int i=b;i<e;++i){
    OFF[i]=excl; CUR[i]=excl; excl += CNT[i];
  }
  if (tid==1023) OFF[NN] = sums[1023];
}

__global__ void k_scatter(const int* __restrict__ ei, int* __restrict__ cur,
                          int* __restrict__ csr, int* __restrict__ srcs){
  int e = blockIdx.x*256 + threadIdx.x;
  if (e < EE){
    int s = ei[e], d = ei[EE+e];
    int p = atomicAdd(&cur[d], 1);
    csr[p] = e; srcs[p] = s;
  }
}

// ---------------- weight prep: bf16 transposed [n][k] layouts ----------------
// 0:ee1t 4096:ee2t 8192:we1t 16384:we2t 20480:ne1t 53248:ne2t 61440:g1lt 69632:g1rt
// 77824:g2lt 86016:g2rt   total 94208
__global__ __launch_bounds__(256) void k_prep(const float* __restrict__ W_ee1,
    const float* __restrict__ W_ee2, const float* __restrict__ W_g1we,
    const float* __restrict__ W_g2we, const float* __restrict__ W_ne1,
    const float* __restrict__ W_ne2, const float* __restrict__ W_g1l,
    const float* __restrict__ W_g1r, const float* __restrict__ W_g2l,
    const float* __restrict__ W_g2r, u16* __restrict__ TW){
  int i = blockIdx.x*256 + threadIdx.x;
  if (i < 4096){
    int n=i>>6, k=i&63; TW[i] = f2bf(W_ee1[k*64+n]);
  } else if (i < 8192){
    int j=i-4096; int n=j>>6, k=j&63; TW[i] = f2bf(W_ee2[k*64+n]);
  } else if (i < 16384){
    int j=i-8192; int n=j>>6, k=j&63; TW[i] = f2bf(W_g1we[k*128+n]);
  } else if (i < 20480){
    int j=i-16384; int n=j>>6, k=j&63; TW[i] = f2bf(W_g2we[k*64+n]);
  } else if (i < 53248){
    int j=i-20480; int n=j>>8, k=j&255; TW[i] = f2bf(W_ne1[k*128+n]);
  } else if (i < 61440){
    int j=i-53248; int n=j>>7, k=j&127; TW[i] = f2bf(W_ne2[k*64+n]);
  } else if (i < 69632){
    int j=i-61440; int n=j>>6, k=j&63; TW[i] = f2bf(W_g1l[k*128+n]);
  } else if (i < 77824){
    int j=i-69632; int n=j>>6, k=j&63; TW[i] = f2bf(W_g1r[k*128+n]);
  } else if (i < 86016){
    int j=i-77824; int n=j>>7, k=j&127; TW[i] = f2bf(W_g2l[k*64+n]);
  } else if (i < 94208){
    int j=i-86016; int n=j>>7, k=j&127; TW[i] = f2bf(W_g2r[k*64+n]);
  }
}

// ---------------- MFMA linear: Y = act(X @ W + b), 64 rows/block ----------------
template<int CI, int CO, int ACT, int BFO, int BFI>
__global__ __launch_bounds__(256) void k_linm(const void* __restrict__ Xv, const u16* __restrict__ WT,
    const float* __restrict__ Bb, void* __restrict__ Yv, int R){
  __shared__ u16 xs[64*(CI+8)];
  int tid = threadIdx.x;
  int r0 = blockIdx.x*64;
  if (BFI){
    const u16* X = (const u16*)Xv;
    for (int i=tid; i<64*CI/8; i+=256){
      int row = i/(CI/8), c = i%(CI/8);
      uint4 v = make_uint4(0,0,0,0);
      if (r0+row < R) v = ((const uint4*)(X + (size_t)(r0+row)*CI))[c];
      *(uint4*)&xs[row*(CI+8) + c*8] = v;
    }
  } else {
    const float* X = (const float*)Xv;
    for (int i=tid; i<64*CI/4; i+=256){
      int row = i/(CI/4), c = i%(CI/4);
      float4 v = make_float4(0,0,0,0);
      if (r0+row < R) v = ((const float4*)(X + (size_t)(r0+row)*CI))[c];
      *(uint2*)&xs[row*(CI+8) + c*4] = make_uint2(pk2(v.x,v.y), pk2(v.z,v.w));
    }
  }
  __syncthreads();
  int l = tid & 63, w = tid >> 6;
  int am = l & 15, kg = l >> 4;
  const int NT = CO/16;
  f32x4 acc[NT];
#pragma unroll
  for (int nt=0;nt<NT;++nt) acc[nt] = (f32x4){0.f,0.f,0.f,0.f};
#pragma unroll
  for (int kc=0; kc<CI/32; ++kc){
    short8v a = *(const short8v*)&xs[(w*16+am)*(CI+8) + kc*32 + kg*8];
#pragma unroll
    for (int nt=0;nt<NT;++nt){
      short8v b = *(const short8v*)&WT[(size_t)(nt*16+am)*CI + kc*32 + kg*8];
      acc[nt] = __builtin_amdgcn_mfma_f32_16x16x32_bf16(a, b, acc[nt], 0, 0, 0);
    }
  }
#pragma unroll
  for (int nt=0;nt<NT;++nt){
    int col = nt*16 + am;
    float bb = Bb[col];
#pragma unroll
    for (int j=0;j<4;++j){
      int row = r0 + w*16 + kg*4 + j;
      if (row < R){
        float v = acc[nt][j] + bb;
        if (ACT==1) v = fmaxf(v, 0.f);
        if (BFO) ((u16*)Yv)[(size_t)row*CO + col] = f2bf(v);
        else     ((float*)Yv)[(size_t)row*CO + col] = v;
      }
    }
  }
}

// ---------------- dual MFMA linear: Y1 = X@W1+b1, Y2 = X@W2+b2 (bf16 out) ----------------
template<int CI, int CO>
__global__ __launch_bounds__(256) void k_linm2(const float* __restrict__ X,
    const u16* __restrict__ WT1, const float* __restrict__ B1,
    const u16* __restrict__ WT2, const float* __restrict__ B2,
    u16* __restrict__ Y1, u16* __restrict__ Y2, int R){
  __shared__ u16 xs[64*(CI+8)];
  int tid = threadIdx.x;
  int r0 = blockIdx.x*64;
  for (int i=tid; i<64*CI/4; i+=256){
    int row = i/(CI/4), c = i%(CI/4);
    float4 v = make_float4(0,0,0,0);
    if (r0+row < R) v = ((const float4*)(X + (size_t)(r0+row)*CI))[c];
    *(uint2*)&xs[row*(CI+8) + c*4] = make_uint2(pk2(v.x,v.y), pk2(v.z,v.w));
  }
  __syncthreads();
  int l = tid & 63, w = tid >> 6;
  int am = l & 15, kg = l >> 4;
  const int NT = CO/16;
  f32x4 acc1[NT], acc2[NT];
#pragma unroll
  for (int nt=0;nt<NT;++nt){ acc1[nt] = (f32x4){0.f,0.f,0.f,0.f}; acc2[nt] = (f32x4){0.f,0.f,0.f,0.f}; }
#pragma unroll
  for (int kc=0; kc<CI/32; ++kc){
    short8v a = *(const short8v*)&xs[(w*16+am)*(CI+8) + kc*32 + kg*8];
#pragma unroll
    for (int nt=0;nt<NT;++nt){
      short8v b1 = *(const short8v*)&WT1[(size_t)(nt*16+am)*CI + kc*32 + kg*8];
      acc1[nt] = __builtin_amdgcn_mfma_f32_16x16x32_bf16(a, b1, acc1[nt], 0, 0, 0);
      short8v b2 = *(const short8v*)&WT2[(size_t)(nt*16+am)*CI + kc*32 + kg*8];
      acc2[nt] = __builtin_amdgcn_mfma_f32_16x16x32_bf16(a, b2, acc2[nt], 0, 0, 0);
    }
  }
#pragma unroll
  for (int nt=0;nt<NT;++nt){
    int col = nt*16 + am;
    float bb1 = B1[col], bb2 = B2[col];
#pragma unroll
    for (int j=0;j<4;++j){
      int row = r0 + w*16 + kg*4 + j;
      if (row < R){
        Y1[(size_t)row*CO + col] = f2bf(acc1[nt][j] + bb1);
        Y2[(size_t)row*CO + col] = f2bf(acc2[nt][j] + bb2);
      }
    }
  }
}

// ---------------- mega1: alpha1 + edge encoder, EDGE-ID order, 64 edges/block ----------------
// round-16 structure: ea staged via LDS (48 VGPR, 55% occupancy — best measured variant)
__global__ __launch_bounds__(256) void k_mega1(const float* __restrict__ EA,
    const int* __restrict__ EI,
    const u16* __restrict__ TW, const float* __restrict__ B1, const float* __restrict__ B2,
    const u16* __restrict__ XLb, const u16* __restrict__ XRb, const float* __restrict__ ATT,
    float* __restrict__ OUT_ER, float* __restrict__ ALPHA){
  __shared__ u16 buf_s[64*72];       // ea (phase 1) then mid (phase 2)
  __shared__ u16 xsum[64*136];       // bf16(xl+xr); later reused as er f32 [64][68]
  __shared__ float al_s[256];
  __shared__ int ssrc[64], sdst[64];
  float* er_s = (float*)xsum;        // alias
  int tid = threadIdx.x;
  int e0 = blockIdx.x*64;
  if (tid < 64){ ssrc[tid]=EI[e0+tid]; sdst[tid]=EI[EE+e0+tid]; }
  __syncthreads();
#pragma unroll
  for (int i=0;i<4;++i){
    int item = tid + i*256;
    int row = item>>4, c4 = item&15;
    float4 v = ((const float4*)(EA + (size_t)(e0+row)*64))[c4];
    *(uint2*)&buf_s[row*72 + c4*4] = make_uint2(pk2(v.x,v.y), pk2(v.z,v.w));
  }
#pragma unroll
  for (int i=0;i<4;++i){
    int item = tid + i*256;
    int row = item>>4, c = item&15;
    uint4 xa = ((const uint4*)(XLb + (size_t)ssrc[row]*128))[c];
    uint4 xb = ((const uint4*)(XRb + (size_t)sdst[row]*128))[c];
    uint4 r;
    r.x = addpk(xa.x, xb.x); r.y = addpk(xa.y, xb.y);
    r.z = addpk(xa.z, xb.z); r.w = addpk(xa.w, xb.w);
    *(uint4*)&xsum[row*136 + c*8] = r;
  }
  __syncthreads();
  int l = tid & 63, w = tid >> 6;
  int am = l & 15, kg = l >> 4;
  short8v a0 = *(const short8v*)&buf_s[(w*16+am)*72 + kg*8];
  short8v a1 = *(const short8v*)&buf_s[(w*16+am)*72 + 32 + kg*8];
  // --- alpha1 we1 GEMM (64->128) + epilogue ---
  {
    f32x4 accw[8];
#pragma unroll
    for (int nt=0;nt<8;++nt) accw[nt] = (f32x4){0.f,0.f,0.f,0.f};
#pragma unroll
    for (int nt=0;nt<8;++nt){
      short8v b0 = *(const short8v*)&TW[8192 + (nt*16+am)*64 + 0  + kg*8];
      short8v b1 = *(const short8v*)&TW[8192 + (nt*16+am)*64 + 32 + kg*8];
      accw[nt] = __builtin_amdgcn_mfma_f32_16x16x32_bf16(a0, b0, accw[nt], 0, 0, 0);
      accw[nt] = __builtin_amdgcn_mfma_f32_16x16x32_bf16(a1, b1, accw[nt], 0, 0, 0);
    }
    float attv[8];
#pragma unroll
    for (int nt=0;nt<8;++nt) attv[nt] = ATT[nt*16 + am];
#pragma unroll
    for (int j=0;j<4;++j){
      int eloc = w*16 + kg*4 + j;
      const u16* xsp = &xsum[eloc*136 + am];
#pragma unroll
      for (int h=0;h<4;++h){
        float sum = 0.f;
#pragma unroll
        for (int q=0;q<2;++q){
          int nt = h*2 + q;
          float s = accw[nt][j] + bf2f(xsp[nt*16]);
          s = s>0.f ? s : 0.2f*s;
          sum += s * attv[nt];
        }
        sum += __shfl_xor(sum,1); sum += __shfl_xor(sum,2);
        sum += __shfl_xor(sum,4); sum += __shfl_xor(sum,8);
        if (am==0) al_s[eloc*4 + h] = sum;
      }
    }
  }
  __syncthreads();   // frag reads + xsum reads complete
  // --- edge encoder layer 1 -> mid (into buf_s) ---
  {
    f32x4 acc[4];
#pragma unroll
    for (int nt=0;nt<4;++nt) acc[nt] = (f32x4){0.f,0.f,0.f,0.f};
#pragma unroll
    for (int nt=0;nt<4;++nt){
      short8v b0 = *(const short8v*)&TW[(nt*16+am)*64 + 0  + kg*8];
      short8v b1 = *(const short8v*)&TW[(nt*16+am)*64 + 32 + kg*8];
      acc[nt] = __builtin_amdgcn_mfma_f32_16x16x32_bf16(a0, b0, acc[nt], 0, 0, 0);
      acc[nt] = __builtin_amdgcn_mfma_f32_16x16x32_bf16(a1, b1, acc[nt], 0, 0, 0);
    }
#pragma unroll
    for (int nt=0;nt<4;++nt){
      int col = nt*16 + am;
      float bb = B1[col];
#pragma unroll
      for (int j=0;j<4;++j){
        float v = fmaxf(acc[nt][j] + bb, 0.f);
        buf_s[(w*16 + kg*4 + j)*72 + col] = f2bf(v);
      }
    }
  }
  __syncthreads();
  // --- edge encoder layer 2 -> er_s (aliases xsum) ---
  {
    short8v m0 = *(const short8v*)&buf_s[(w*16+am)*72 + 0  + kg*8];
    short8v m1 = *(const short8v*)&buf_s[(w*16+am)*72 + 32 + kg*8];
    f32x4 acc2[4];
#pragma unroll
    for (int nt=0;nt<4;++nt) acc2[nt] = (f32x4){0.f,0.f,0.f,0.f};
#pragma unroll
    for (int nt=0;nt<4;++nt){
      short8v b0 = *(const short8v*)&TW[4096 + (nt*16+am)*64 + 0  + kg*8];
      short8v b1 = *(const short8v*)&TW[4096 + (nt*16+am)*64 + 32 + kg*8];
      acc2[nt] = __builtin_amdgcn_mfma_f32_16x16x32_bf16(m0, b0, acc2[nt], 0, 0, 0);
      acc2[nt] = __builtin_amdgcn_mfma_f32_16x16x32_bf16(m1, b1, acc2[nt], 0, 0, 0);
    }
#pragma unroll
    for (int nt=0;nt<4;++nt){
      int col = nt*16 + am;
      float bb = B2[col];
#pragma unroll
      for (int j=0;j<4;++j) er_s[(w*16 + kg*4 + j)*68 + col] = acc2[nt][j] + bb;
    }
  }
  __syncthreads();
  ALPHA[(size_t)e0*4 + tid] = al_s[tid];
  {
    int col4 = tid & 15;
#pragma unroll
    for (int p=0;p<4;++p){
      int row = p*16 + (tid>>4);
      float4 v = *(const float4*)&er_s[row*68 + col4*4];
      *(float4*)(OUT_ER + (size_t)(e0+row)*64 + col4*4) = v;
    }
  }
}

// ---------------- alpha2: EDGE-ID order, direct A-frags, xsum epilogue (H=2, HD=64) --------
__global__ __launch_bounds__(256) void k_alpha2m(const float* __restrict__ EA,
    const int* __restrict__ EI,
    const u16* __restrict__ TW, const u16* __restrict__ XLb, const u16* __restrict__ XRb,
    const float* __restrict__ ATT, float* __restrict__ ALPHA){
  __shared__ u16 xsum[64*72];
  __shared__ float al_s[128];
  __shared__ int ssrc[64], sdst[64];
  int tid = threadIdx.x;
  int e0 = blockIdx.x*64;
  if (tid < 64){ ssrc[tid]=EI[e0+tid]; sdst[tid]=EI[EE+e0+tid]; }
  __syncthreads();
#pragma unroll
  for (int i=0;i<2;++i){
    int item = tid + i*256;
    int row = item>>3, c = item&7;
    uint4 xa = ((const uint4*)(XLb + (size_t)ssrc[row]*64))[c];
    uint4 xb = ((const uint4*)(XRb + (size_t)sdst[row]*64))[c];
    uint4 r;
    r.x = addpk(xa.x, xb.x); r.y = addpk(xa.y, xb.y);
    r.z = addpk(xa.z, xb.z); r.w = addpk(xa.w, xb.w);
    *(uint4*)&xsum[row*72 + c*8] = r;
  }
  int l = tid & 63, w = tid >> 6;
  int am = l & 15, kg = l >> 4;
  const float* arow = EA + (size_t)(e0 + w*16 + am)*64;
  float4 f0 = *(const float4*)(arow + kg*8);
  float4 f1 = *(const float4*)(arow + kg*8 + 4);
  float4 f2 = *(const float4*)(arow + 32 + kg*8);
  float4 f3 = *(const float4*)(arow + 32 + kg*8 + 4);
  uint4 ua, ub;
  ua.x = pk2(f0.x,f0.y); ua.y = pk2(f0.z,f0.w); ua.z = pk2(f1.x,f1.y); ua.w = pk2(f1.z,f1.w);
  ub.x = pk2(f2.x,f2.y); ub.y = pk2(f2.z,f2.w); ub.z = pk2(f3.x,f3.y); ub.w = pk2(f3.z,f3.w);
  short8v a0 = *(short8v*)&ua;
  short8v a1 = *(short8v*)&ub;
  f32x4 acc[4];
#pragma unroll
  for (int nt=0;nt<4;++nt) acc[nt] = (f32x4){0.f,0.f,0.f,0.f};
#pragma unroll
  for (int nt=0;nt<4;++nt){
    short8v b0 = *(const short8v*)&TW[16384 + (nt*16+am)*64 + 0  + kg*8];
    short8v b1 = *(const short8v*)&TW[16384 + (nt*16+am)*64 + 32 + kg*8];
    acc[nt] = __builtin_amdgcn_mfma_f32_16x16x32_bf16(a0, b0, acc[nt], 0, 0, 0);
    acc[nt] = __builtin_amdgcn_mfma_f32_16x16x32_bf16(a1, b1, acc[nt], 0, 0, 0);
  }
  __syncthreads();   // xsum ready
  float attv[4];
#pragma unroll
  for (int nt=0;nt<4;++nt) attv[nt] = ATT[nt*16 + am];
#pragma unroll
  for (int j=0;j<4;++j){
    int eloc = w*16 + kg*4 + j;
    const u16* xsp = &xsum[eloc*72 + am];
#pragma unroll
    for (int h=0;h<2;++h){
      float sum = 0.f;
#pragma unroll
      for (int q=0;q<2;++q){
        int nt = h*2 + q;
        float s = acc[nt][j] + bf2f(xsp[nt*16]);
        s = s>0.f ? s : 0.2f*s;
        sum += s * attv[nt];
      }
      sum += __shfl_xor(sum,1); sum += __shfl_xor(sum,2);
      sum += __shfl_xor(sum,4); sum += __shfl_xor(sum,8);
      if (am==0) al_s[eloc*2 + h] = sum;
    }
  }
  __syncthreads();
  if (tid < 128) ALPHA[(size_t)e0*2 + tid] = al_s[tid];
}

// ---------------- gather layer 1: online softmax + LN + ELU fused ----------------
__global__ __launch_bounds__(256) void k_gather1(const u16* __restrict__ XLb, const float* __restrict__ ALPHA,
    const float* __restrict__ BIAS, const float* __restrict__ G_, const float* __restrict__ B_,
    const int* __restrict__ CSR, const int* __restrict__ SRCS, const int* __restrict__ OFF,
    float* __restrict__ OUT){
  int t = threadIdx.x & 63;
  int n = blockIdx.x*4 + (threadIdx.x >> 6);
  int h = t >> 4;
  int beg = OFF[n], end = OFF[n+1];
  float m = -INFINITY, l = 0.f, a0 = 0.f, a1 = 0.f;
  for (int i=beg; i<end; ++i){
    int e = CSR[i];
    int s = SRCS[i];
    float al = ALPHA[(size_t)e*4 + h];
    u32 v = *(const u32*)(XLb + (size_t)s*128 + 2*t);
    float x0 = __uint_as_float(v<<16);
    float x1 = __uint_as_float(v & 0xffff0000u);
    if (al > m){
      float sc = __expf(m - al);   // m==-inf -> 0
      a0 = a0*sc + x0; a1 = a1*sc + x1; l = l*sc + 1.f; m = al;
    } else {
      float p = __expf(al - m);
      a0 += p*x0; a1 += p*x1; l += p;
    }
  }
  float inv = 1.f/(l + 1e-16f);
  float o0 = a0*inv + BIAS[2*t];
  float o1 = a1*inv + BIAS[2*t+1];
  float s = o0 + o1, q = o0*o0 + o1*o1;
#pragma unroll
  for (int o=1;o<64;o<<=1){ s += __shfl_xor(s,o); q += __shfl_xor(q,o); }
  float mean = s * (1.f/128.f);
  float var  = q * (1.f/128.f) - mean*mean;
  float r = rsqrtf(var + 1e-5f);
  float y0 = (o0-mean)*r*G_[2*t]   + B_[2*t];
  float y1 = (o1-mean)*r*G_[2*t+1] + B_[2*t+1];
  y0 = y0>0.f ? y0 : __expf(y0)-1.f;
  y1 = y1>0.f ? y1 : __expf(y1)-1.f;
  *(float2*)(OUT + (size_t)n*128 + 2*t) = make_float2(y0,y1);
}

// ---------------- gather layer 2: online softmax, raw out (no LDS, high occupancy) ----------------
__global__ __launch_bounds__(256) void k_gather2(const u16* __restrict__ XLb, const float* __restrict__ ALPHA,
    const float* __restrict__ BIAS, const int* __restrict__ CSR, const int* __restrict__ SRCS,
    const int* __restrict__ OFF, float* __restrict__ OUT){
  int t = threadIdx.x & 63;
  int n = blockIdx.x*4 + (threadIdx.x >> 6);
  int h = t >> 5;
  int beg = OFF[n], end = OFF[n+1];
  float m = -INFINITY, l = 0.f, a0 = 0.f;
  for (int i=beg; i<end; ++i){
    int e = CSR[i];
    int s = SRCS[i];
    float al = ALPHA[(size_t)e*2 + h];
    float xlv = bf2f(XLb[(size_t)s*64 + t]);
    if (al > m){
      float sc = __expf(m - al);
      a0 = a0*sc + xlv; l = l*sc + 1.f; m = al;
    } else {
      float p = __expf(al - m);
      a0 += p*xlv; l += p;
    }
  }
  float inv = 1.f/(l + 1e-16f);
  OUT[(size_t)n*64 + t] = a0*inv + BIAS[t];
}

// ---------------- LN(64) + residual GEMV + ELU + gate MLP fused (LDS GEMV) ----------------
__global__ __launch_bounds__(256) void k_res_gate(const float* __restrict__ GO, const float* __restrict__ H0,
    const float* __restrict__ RPW, const float* __restrict__ RPB_, const float* __restrict__ G_,
    const float* __restrict__ B_, const float* __restrict__ GT1, const float* __restrict__ GTB1,
    const float* __restrict__ GT2, const float* __restrict__ GTB2,
    float* __restrict__ NE, float* __restrict__ GATE){
  __shared__ float rlt[64*68];
  __shared__ float glt[64*68];
  __shared__ float xsw[4][64];
  __shared__ float ysw[4][64];
  int tid = threadIdx.x, t = tid & 63, wv = tid >> 6;
  for (int i=tid; i<64*64; i+=256){
    int k = i>>6, c = i&63;
    rlt[c*68+k] = RPW[i];
    glt[c*68+k] = GT1[i];
  }
  __syncthreads();
  int n = blockIdx.x*4 + wv;
  float x = GO[(size_t)n*64 + t];
  float s = x, q = x*x;
#pragma unroll
  for (int o=1;o<64;o<<=1){ s += __shfl_xor(s,o); q += __shfl_xor(q,o); }
  float mean = s * (1.f/64.f);
  float var  = q * (1.f/64.f) - mean*mean;
  float r = rsqrtf(var + 1e-5f);
  float ln = (x-mean)*r*G_[t] + B_[t];
  xsw[wv][t] = H0[(size_t)n*64 + t];   // same-wave write->read, lockstep safe
  float acc = 0.f;
#pragma unroll
  for (int k4=0;k4<16;++k4){
    float4 w  = *(const float4*)&rlt[t*68 + k4*4];
    float4 xv = *(const float4*)&xsw[wv][k4*4];
    acc += xv.x*w.x + xv.y*w.y + xv.z*w.z + xv.w*w.w;
  }
  float y = ln + acc + RPB_[t];
  y = y>0.f ? y : __expf(y)-1.f;
  NE[(size_t)n*64+t] = y;
  ysw[wv][t] = y;
  float mid = 0.f;
#pragma unroll
  for (int k4=0;k4<16;++k4){
    float4 w  = *(const float4*)&glt[t*68 + k4*4];
    float4 xv = *(const float4*)&ysw[wv][k4*4];
    mid += xv.x*w.x + xv.y*w.y + xv.z*w.z + xv.w*w.w;
  }
  float p = fmaxf(mid + GTB1[t], 0.f) * GT2[t];
#pragma unroll
  for (int o=1;o<64;o<<=1) p += __shfl_xor(p,o);
  if (t==0) GATE[n] = p + GTB2[0];
}

// ---------------- pooling ----------------
__global__ __launch_bounds__(256) void k_pool_max(const float* __restrict__ GATE, const int* __restrict__ BATCH, u32* __restrict__ GMAX){
  __shared__ u32 lmax[GG];
  int tid = threadIdx.x;
  if (tid < GG) lmax[tid] = 0u;
  __syncthreads();
  int base = blockIdx.x*1024;
#pragma unroll
  for (int j=0;j<4;++j){
    int i = base + j*256 + tid;
    if (i < NN) atomicMax(&lmax[BATCH[i]], encf(GATE[i]));
  }
  __syncthreads();
  if (tid < GG && lmax[tid] != 0u) atomicMax(&GMAX[tid], lmax[tid]);
}

__global__ __launch_bounds__(64) void k_pool_acc(const float* __restrict__ NE, const float* __restrict__ GATE,
    const int* __restrict__ BATCH, const u32* __restrict__ GMAX, float* __restrict__ GACC, float* __restrict__ GDEN){
  int t = threadIdx.x;
  int n0 = blockIdx.x*256;
  int n1 = n0+256; if (n1 > NN) n1 = NN;
  int curg = -1; float acc = 0.f, dl = 0.f, gm = 0.f;
  for (int n=n0; n<n1; ++n){
    int g = BATCH[n];
    if (g != curg){
      if (curg >= 0){ atomicAdd(&GACC[curg*64+t], acc); if (t==0) atomicAdd(&GDEN[curg], dl); }
      curg = g; acc = 0.f; dl = 0.f;
      float d = decf(GMAX[g]);
      gm = isfinite(d) ? d : 0.f;
    }
    float p = __expf(GATE[n] - gm);
    acc += p * NE[(size_t)n*64 + t];
    if (t==0) dl += p;
  }
  if (curg >= 0){ atomicAdd(&GACC[curg*64+t], acc); if (t==0) atomicAdd(&GDEN[curg], dl); }
}

__global__ __launch_bounds__(64) void k_scene(const float* __restrict__ GACC, const float* __restrict__ GDEN,
    const float* __restrict__ W1, const float* __restrict__ B1, const float* __restrict__ W2,
    const float* __restrict__ B2, float* __restrict__ Z){
  __shared__ float gv[GG][64];
  __shared__ float md[GG][64];
  int t = threadIdx.x;
  for (int g=0; g<GG; ++g) gv[g][t] = GACC[g*64+t] / (GDEN[g] + 1e-16f);
  __syncthreads();
  for (int g=0; g<GG; ++g){
    float m = 0.f;
    for (int k=0;k<64;++k) m += gv[g][k]*W1[k*64+t];
    md[g][t] = fmaxf(m + B1[t], 0.f);
  }
  __syncthreads();
  if (t < 32){
    for (int g=0; g<GG; ++g){
      float o = 0.f;
      for (int k=0;k<64;++k) o += md[g][k]*W2[k*32+t];
      Z[g*32+t] = o + B2[t];
    }
  }
}

// ---------------- launch ----------------
extern "C" void kernel_launch(void* const* d_in, const int* in_sizes, int n_in,
                              void* d_out, int out_size, void* d_ws, size_t ws_size,
                              hipStream_t stream){
  const float* x   = (const float*)d_in[0];
  const int* ei    = (const int*)d_in[1];
  const float* ea  = (const float*)d_in[2];
  const int* batch = (const int*)d_in[3];
  const float* ne_w1 = (const float*)d_in[4];  const float* ne_b1 = (const float*)d_in[5];
  const float* ne_w2 = (const float*)d_in[6];  const float* ne_b2 = (const float*)d_in[7];
  const float* ee_w1 = (const float*)d_in[8];  const float* ee_b1 = (const float*)d_in[9];
  const float* ee_w2 = (const float*)d_in[10]; const float* ee_b2 = (const float*)d_in[11];
  const float* g1_wl = (const float*)d_in[12]; const float* g1_bl = (const float*)d_in[13];
  const float* g1_wr = (const float*)d_in[14]; const float* g1_br = (const float*)d_in[15];
  const float* g1_we = (const float*)d_in[16];
  const float* g1_att= (const float*)d_in[17]; const float* g1_b  = (const float*)d_in[18];
  const float* n1_g  = (const float*)d_in[19]; const float* n1_b  = (const float*)d_in[20];
  const float* g2_wl = (const float*)d_in[21]; const float* g2_bl = (const float*)d_in[22];
  const float* g2_wr = (const float*)d_in[23]; const float* g2_br = (const float*)d_in[24];
  const float* g2_we = (const float*)d_in[25];
  const float* g2_att= (const float*)d_in[26]; const float* g2_b  = (const float*)d_in[27];
  const float* n2_g  = (const float*)d_in[28]; const float* n2_b  = (const float*)d_in[29];
  const float* rp_w  = (const float*)d_in[30]; const float* rp_b  = (const float*)d_in[31];
  const float* gt_w1 = (const float*)d_in[32]; const float* gt_b1 = (const float*)d_in[33];
  const float* gt_w2 = (const float*)d_in[34]; const float* gt_b2 = (const float*)d_in[35];
  const float* se_w1 = (const float*)d_in[36]; const float* se_b1 = (const float*)d_in[37];
  const float* se_w2 = (const float*)d_in[38]; const float* se_b2 = (const float*)d_in[39];

  char* ws = (char*)d_ws;
  size_t o = 0;
  auto alloc = [&](size_t bytes){ size_t r = o; o += (bytes + 255) & ~(size_t)255; return r; };
  float* h0    = (float*)(ws + alloc((size_t)NN*64*4));
  float* ta    = (float*)(ws + alloc((size_t)NN*128*4));   // node-enc mid (bf16), then alpha buffer
  float* tc    = (float*)(ws + alloc((size_t)NN*128*4));   // h1, then gather2 out
  u16*   xl1b  = (u16*)  (ws + alloc((size_t)NN*128*2));
  u16*   xr1b  = (u16*)  (ws + alloc((size_t)NN*128*2));
  u16*   xl2b  = (u16*)  (ws + alloc((size_t)NN*64*2));
  u16*   xr2b  = (u16*)  (ws + alloc((size_t)NN*64*2));
  float* gate  = (float*)(ws + alloc((size_t)NN*4));
  int*   cnt   = (int*)  (ws + alloc((size_t)NN*4));
  int*   off   = (int*)  (ws + alloc((size_t)(NN+1)*4));
  int*   csr   = (int*)  (ws + alloc((size_t)EE*4));
  int*   srcs  = (int*)  (ws + alloc((size_t)EE*4));
  u16*   tw    = (u16*)  (ws + alloc((size_t)94208*2));
  char*  poolb = ws + alloc(4096);
  u32*   gmax  = (u32*)poolb;
  float* gden  = (float*)(poolb + 64);
  float* gacc  = (float*)(poolb + 128);
  float* alphab= ta;                                       // alias: ta free after node encoder
  u16*   midb  = (u16*)ta;                                 // node-enc mid bf16 (dead before alpha)
  if (o > ws_size) return;

  float* out_z  = (float*)d_out;
  float* out_ne = out_z + 256;
  float* out_er = out_ne + (size_t)NN*64;

  // CSR by dst + weight prep
  hipMemsetAsync(cnt, 0, (size_t)NN*4, stream);
  hipMemsetAsync(poolb, 0, 4096, stream);
  k_count<<<(EE+255)/256, 256, 0, stream>>>(ei, cnt);
  k_scan<<<1, 1024, 0, stream>>>(cnt, off, cnt);
  k_scatter<<<(EE+255)/256, 256, 0, stream>>>(ei, cnt, csr, srcs);
  k_prep<<<368, 256, 0, stream>>>(ee_w1, ee_w2, g1_we, g2_we, ne_w1, ne_w2,
                                  g1_wl, g1_wr, g2_wl, g2_wr, tw);

  // node encoder (MFMA): x -> midb(bf16) -> h0(f32)
  k_linm<256,128,1,1,0><<<(NN+63)/64, 256, 0, stream>>>(x,    tw+20480, ne_b1, midb, NN);
  k_linm<128,64, 0,0,1><<<(NN+63)/64, 256, 0, stream>>>(midb, tw+53248, ne_b2, h0,   NN);

  // GAT layer 1 (+ fused edge encoder), edge-id order
  k_linm2<64,128><<<(NN+63)/64, 256, 0, stream>>>(h0, tw+61440, g1_bl, tw+69632, g1_br, xl1b, xr1b, NN);
  k_mega1<<<EE/64, 256, 0, stream>>>(ea, ei, tw, ee_b1, ee_b2,
                                     xl1b, xr1b, g1_att, out_er, alphab);
  k_gather1<<<NN/4, 256, 0, stream>>>(xl1b, alphab, g1_b, n1_g, n1_b, csr, srcs, off, tc);

  // GAT layer 2, edge-id order
  k_linm2<128,64><<<(NN+63)/64, 256, 0, stream>>>(tc, tw+77824, g2_bl, tw+86016, g2_br, xl2b, xr2b, NN);
  k_alpha2m<<<EE/64, 256, 0, stream>>>(ea, ei, tw, xl2b, xr2b, g2_att, alphab);
  k_gather2<<<NN/4, 256, 0, stream>>>(xl2b, alphab, g2_b, csr, srcs, off, tc);
  k_res_gate<<<NN/4, 256, 0, stream>>>(tc, h0, rp_w, rp_b, n2_g, n2_b,
                                       gt_w1, gt_b1, gt_w2, gt_b2, out_ne, gate);

  // pooling + scene encoder
  k_pool_max<<<(NN+1023)/1024, 256, 0, stream>>>(gate, batch, gmax);
  k_pool_acc<<<(NN+255)/256, 64, 0, stream>>>(out_ne, gate, batch, gmax, gacc, gden);
  k_scene<<<1, 64, 0, stream>>>(gacc, gden, se_w1, se_b1, se_w2, se_b2, out_z);
}